// Round 3
// baseline (680.390 us; speedup 1.0000x reference)
//
#include <hip/hip_runtime.h>
#include <hip/hip_bf16.h>

using bf16 = __hip_bfloat16;
typedef __attribute__((ext_vector_type(8))) short short8;   // 8 x bf16 (4 VGPRs)
typedef __attribute__((ext_vector_type(4))) float f32x4;

#define B_   16
#define C_   512
#define N_   4096
#define NG   8
#define GRP_ELEMS (64 * 4096)   // channels/group * spatial = 262144
static constexpr float kScale = 0.04419417382415922f;  // 512^-0.5

// ---------------- memory layout ----------------
// d_ws (needs 196 MB):
//   WQ 1.5MB | WP 0.5MB | STATS | Q 64MB | K 64MB | VT 64MB
//   attn (8MB) aliases Q (q dead after QK^T); O_t (64MB) aliases K.
// d_out (128 MB f32) doubles as scratch for dead-range intermediates:
//   xn_t bf16 64MB (dead after QKV), then S f32 16MB (written after xn_t dead).
//   Final proj kernel rewrites all of d_out.
#define OFF_WQ    0ULL
#define OFF_WP    0x180000ULL
#define OFF_STATS 0x200000ULL
#define OFF_Q     0x400000ULL
#define OFF_K     (OFF_Q  + 0x4000000ULL)
#define OFF_VT    (OFF_K  + 0x4000000ULL)
#define OFF_ATT   OFF_Q
#define OFF_OT    OFF_K

typedef __attribute__((address_space(1))) const void* as1cvp;
typedef __attribute__((address_space(3))) void* as3vp;

__device__ inline void gload_lds16(const void* g, void* l) {
  __builtin_amdgcn_global_load_lds((as1cvp)g, (as3vp)l, 16, 0, 0);
}

// ---------------- K0: fp32 weights -> bf16 ----------------
__global__ __launch_bounds__(256) void cvt_weights(const float* __restrict__ wq,
                                                   const float* __restrict__ wp,
                                                   bf16* __restrict__ oq,
                                                   bf16* __restrict__ op) {
  int i = blockIdx.x * 256 + threadIdx.x;
  if (i < 1536 * 512) oq[i] = __float2bfloat16(wq[i]);
  if (i < 512 * 512)  op[i] = __float2bfloat16(wp[i]);
}

// ---------------- K1: GroupNorm stats ----------------
__global__ __launch_bounds__(256) void gn_stats(const float* __restrict__ x,
                                                float* __restrict__ stats) {
  const int bg = blockIdx.x;  // b*8+g, 128 blocks
  const float4* p = (const float4*)(x + (size_t)bg * GRP_ELEMS);
  float s = 0.f, q = 0.f;
  for (int i = threadIdx.x; i < GRP_ELEMS / 4; i += 256) {
    float4 v = p[i];
    s += v.x + v.y + v.z + v.w;
    q += v.x * v.x + v.y * v.y + v.z * v.z + v.w * v.w;
  }
  for (int off = 32; off; off >>= 1) { s += __shfl_xor(s, off); q += __shfl_xor(q, off); }
  __shared__ float red[8];
  int w = threadIdx.x >> 6;
  if ((threadIdx.x & 63) == 0) { red[w] = s; red[4 + w] = q; }
  __syncthreads();
  if (threadIdx.x == 0) {
    float S = red[0] + red[1] + red[2] + red[3];
    float Q = red[4] + red[5] + red[6] + red[7];
    float mean = S * (1.f / GRP_ELEMS);
    float var  = Q * (1.f / GRP_ELEMS) - mean * mean;
    stats[bg * 2]     = mean;
    stats[bg * 2 + 1] = rsqrtf(var + 1e-5f);
  }
}

// ---------------- K2: normalize + affine + transpose -> xn_t (b,n,c) bf16 ----
__global__ __launch_bounds__(256) void gn_apply_t(const float* __restrict__ x,
                                                  const float* __restrict__ stats,
                                                  const float* __restrict__ nw,
                                                  const float* __restrict__ nb,
                                                  bf16* __restrict__ xnt) {
  const int nt = blockIdx.x;   // n tile [0,64)
  const int ct = blockIdx.y;   // c tile == group [0,8)
  const int b  = blockIdx.z;
  __shared__ float tile[64][65];
  const float mean = stats[(b * NG + ct) * 2];
  const float rstd = stats[(b * NG + ct) * 2 + 1];
  const int col = threadIdx.x & 63;
  const int r4  = threadIdx.x >> 6;
#pragma unroll
  for (int p = 0; p < 16; ++p) {
    int cl = p * 4 + r4;
    int c  = ct * 64 + cl;
    float g  = nw[c] * rstd;
    float sh = nb[c] - mean * g;
    float v  = x[((size_t)b * C_ + c) * N_ + nt * 64 + col];
    tile[cl][col] = v * g + sh;
  }
  __syncthreads();
#pragma unroll
  for (int p = 0; p < 16; ++p) {
    int nl = p * 4 + r4;
    xnt[((size_t)b * N_ + nt * 64 + nl) * C_ + ct * 64 + col] =
        __float2bfloat16(tile[col][nl]);
  }
}

// ---------------- generic NT bf16 GEMM, 128x128 tile, BK=32 ----------------
// C[M,N] = A[M,K] * B[N,K]^T  (both K-major).  4 waves (2x2), each 64x64 = 4x4
// frags of mfma_f32_16x16x32_bf16. MODE selects the epilogue.
// MODE 0: QKV   -> q (b,c,n), k (b,c,n), v_t (b,n,c), +bias        [bf16 out]
// MODE 1: QK^T  -> S f32 * alpha, per-batch (blockIdx.z)
// MODE 2: PV    -> O_t (b,n,c) bf16
// MODE 3: proj  -> out f32 = acc + bias[row] + resid               [residual]
template<int MODE>
__global__ __launch_bounds__(256) void gemm_nt(
    const bf16* __restrict__ Ag, const bf16* __restrict__ Bg, int K,
    long long sA, long long sB,
    const float* __restrict__ bias, float alpha,
    void* __restrict__ o0, void* __restrict__ o1, void* __restrict__ o2,
    const float* __restrict__ resid) {
  __shared__ __align__(16) bf16 As[128 * 32];
  __shared__ __align__(16) bf16 Bs[128 * 32];
  const bf16* A = Ag + (size_t)blockIdx.z * sA + (size_t)blockIdx.y * 128 * K;
  const bf16* B = Bg + (size_t)blockIdx.z * sB + (size_t)blockIdx.x * 128 * K;
  const int tid  = threadIdx.x;
  const int lane = tid & 63;
  const int wv   = tid >> 6;
  const int wr = wv >> 1, wc = wv & 1;
  const int r0 = wr * 64, c0 = wc * 64;
  const int mrow = lane & 15, krow = lane >> 4;
  const int i0 = tid, i1 = tid + 256;

  f32x4 acc[4][4];
#pragma unroll
  for (int mi = 0; mi < 4; ++mi)
#pragma unroll
    for (int ni = 0; ni < 4; ++ni)
#pragma unroll
      for (int r = 0; r < 4; ++r) acc[mi][ni][r] = 0.f;

  for (int k0 = 0; k0 < K; k0 += 32) {
    // stage 128x32 A and B tiles; rows contiguous 64B in global (K-major)
    gload_lds16(A + (size_t)(i0 >> 2) * K + k0 + (i0 & 3) * 8, (char*)As + i0 * 16);
    gload_lds16(A + (size_t)(i1 >> 2) * K + k0 + (i1 & 3) * 8, (char*)As + i1 * 16);
    gload_lds16(B + (size_t)(i0 >> 2) * K + k0 + (i0 & 3) * 8, (char*)Bs + i0 * 16);
    gload_lds16(B + (size_t)(i1 >> 2) * K + k0 + (i1 & 3) * 8, (char*)Bs + i1 * 16);
    __syncthreads();  // compiler emits vmcnt(0) drain before barrier
    short8 af[4], bf_[4];
#pragma unroll
    for (int mi = 0; mi < 4; ++mi)
      af[mi] = *(const short8*)((const char*)As + (r0 + mi * 16 + mrow) * 64 + krow * 16);
#pragma unroll
    for (int ni = 0; ni < 4; ++ni)
      bf_[ni] = *(const short8*)((const char*)Bs + (c0 + ni * 16 + mrow) * 64 + krow * 16);
#pragma unroll
    for (int mi = 0; mi < 4; ++mi)
#pragma unroll
      for (int ni = 0; ni < 4; ++ni)
        acc[mi][ni] = __builtin_amdgcn_mfma_f32_16x16x32_bf16(af[mi], bf_[ni],
                                                              acc[mi][ni], 0, 0, 0);
    __syncthreads();
  }

  // epilogue: C(row,col) with row=(lane>>4)*4+r, col=lane&15 per 16x16 frag
#pragma unroll
  for (int mi = 0; mi < 4; ++mi) {
#pragma unroll
    for (int ni = 0; ni < 4; ++ni) {
      const int col_l = c0 + ni * 16 + mrow;
#pragma unroll
      for (int r = 0; r < 4; ++r) {
        const int row_l = r0 + mi * 16 + krow * 4 + r;
        float v = acc[mi][ni][r];
        if constexpr (MODE == 0) {
          int o = blockIdx.y * 128 + row_l;          // 0..1536
          v += bias[o];
          int j = blockIdx.x * 128 + col_l;          // 0..65536
          int bidx = j >> 12, n = j & 4095;
          int which = o >> 9, ol = o & 511;
          if (which == 0)
            ((bf16*)o0)[((size_t)bidx * C_ + ol) * N_ + n] = __float2bfloat16(v);
          else if (which == 1)
            ((bf16*)o1)[((size_t)bidx * C_ + ol) * N_ + n] = __float2bfloat16(v);
          else
            ((bf16*)o2)[((size_t)bidx * N_ + n) * C_ + ol] = __float2bfloat16(v);
        } else if constexpr (MODE == 1) {
          int row = blockIdx.y * 128 + row_l, colg = blockIdx.x * 128 + col_l;
          ((float*)o0)[(size_t)blockIdx.z * 262144 + row * 512 + colg] = v * alpha;
        } else if constexpr (MODE == 2) {
          int row = blockIdx.y * 128 + row_l, colg = blockIdx.x * 128 + col_l;
          ((bf16*)o0)[((size_t)blockIdx.z * N_ + row) * C_ + colg] = __float2bfloat16(v);
        } else {
          int o = blockIdx.y * 128 + row_l;
          int j = blockIdx.x * 128 + col_l;
          int bidx = j >> 12, n = j & 4095;
          size_t addr = ((size_t)bidx * C_ + o) * N_ + n;
          ((float*)o0)[addr] = v + bias[o] + resid[addr];
        }
      }
    }
  }
}

// ---------------- K5: row softmax, S f32 -> attn bf16 ----------------
__global__ __launch_bounds__(256) void softmax_rows(const float* __restrict__ S,
                                                    bf16* __restrict__ att) {
  const int row  = blockIdx.x * 4 + (threadIdx.x >> 6);  // b*512 + c
  const int lane = threadIdx.x & 63;
  const float* p = S + (size_t)row * 512;
  float v[8];
  float mx = -1e30f;
#pragma unroll
  for (int i = 0; i < 8; ++i) { v[i] = p[lane + i * 64]; mx = fmaxf(mx, v[i]); }
  for (int off = 32; off; off >>= 1) mx = fmaxf(mx, __shfl_xor(mx, off));
  float s = 0.f;
#pragma unroll
  for (int i = 0; i < 8; ++i) { v[i] = __expf(v[i] - mx); s += v[i]; }
  for (int off = 32; off; off >>= 1) s += __shfl_xor(s, off);
  float inv = 1.f / s;
  bf16* q = att + (size_t)row * 512;
#pragma unroll
  for (int i = 0; i < 8; ++i) q[lane + i * 64] = __float2bfloat16(v[i] * inv);
}

extern "C" void kernel_launch(void* const* d_in, const int* in_sizes, int n_in,
                              void* d_out, int out_size, void* d_ws, size_t ws_size,
                              hipStream_t stream) {
  const float* x      = (const float*)d_in[0];
  const float* norm_w = (const float*)d_in[1];
  const float* norm_b = (const float*)d_in[2];
  const float* qkv_w  = (const float*)d_in[3];
  const float* qkv_b  = (const float*)d_in[4];
  const float* proj_w = (const float*)d_in[5];
  const float* proj_b = (const float*)d_in[6];
  float* out = (float*)d_out;
  char* ws = (char*)d_ws;

  bf16*  wq    = (bf16*)(ws + OFF_WQ);
  bf16*  wp    = (bf16*)(ws + OFF_WP);
  float* stats = (float*)(ws + OFF_STATS);
  bf16*  q     = (bf16*)(ws + OFF_Q);
  bf16*  k     = (bf16*)(ws + OFF_K);
  bf16*  vt    = (bf16*)(ws + OFF_VT);
  bf16*  att   = (bf16*)(ws + OFF_ATT);   // aliases Q (dead after QK^T)
  bf16*  ot    = (bf16*)(ws + OFF_OT);    // aliases K (dead after QK^T)
  // d_out doubles as scratch for dead-range intermediates:
  bf16*  xnt   = (bf16*)d_out;            // 64 MB, dead after QKV GEMM
  float* S     = (float*)d_out;           // 16 MB, written after xnt dead

  cvt_weights<<<3072, 256, 0, stream>>>(qkv_w, proj_w, wq, wp);
  gn_stats<<<128, 256, 0, stream>>>(x, stats);
  gn_apply_t<<<dim3(64, 8, 16), 256, 0, stream>>>(x, stats, norm_w, norm_b, xnt);
  // QKV: M=1536 (o), N=65536 (b*n), K=512
  gemm_nt<0><<<dim3(512, 12, 1), 256, 0, stream>>>(wq, xnt, 512, 0, 0, qkv_b, 1.f,
                                                   q, k, vt, nullptr);
  // QK^T per batch: M=N=512 (c,d), K=4096 (n)
  gemm_nt<1><<<dim3(4, 4, 16), 256, 0, stream>>>(q, k, 4096, 512LL * 4096,
                                                 512LL * 4096, nullptr, kScale,
                                                 S, nullptr, nullptr, nullptr);
  softmax_rows<<<2048, 256, 0, stream>>>(S, att);
  // PV per batch: M=4096 (n), N=512 (c), K=512 (d); A=v_t, B=attn
  gemm_nt<2><<<dim3(4, 32, 16), 256, 0, stream>>>(vt, att, 512, 4096LL * 512,
                                                  512LL * 512, nullptr, 1.f,
                                                  ot, nullptr, nullptr, nullptr);
  // proj: M=512 (o), N=65536 (b*n), K=512 (c); + bias + residual
  gemm_nt<3><<<dim3(512, 4, 1), 256, 0, stream>>>(wp, ot, 512, 0, 0, proj_b, 1.f,
                                                  out, nullptr, nullptr, x);
}

// Round 4
// 649.316 us; speedup vs baseline: 1.0479x; 1.0479x over previous
//
#include <hip/hip_runtime.h>
#include <hip/hip_bf16.h>

using bf16 = __hip_bfloat16;
typedef __attribute__((ext_vector_type(8))) short short8;   // 8 x bf16 (4 VGPRs)
typedef __attribute__((ext_vector_type(4))) float f32x4;

#define B_   16
#define C_   512
#define N_   4096
#define NG   8
#define GRP_ELEMS (64 * 4096)   // channels/group * spatial = 262144
static constexpr float kScale = 0.04419417382415922f;  // 512^-0.5
#define SPART_STRIDE 4194304ULL  // 16*512*512 f32 elements per split-K partial

// ---------------- memory layout ----------------
// d_ws (needs 196 MB):
//   WQ 1.5MB | WP 0.5MB | STATS | Q 64MB | K 64MB | VT 64MB
//   attn (8MB) aliases Q (q dead after QK^T); O_t (64MB) aliases K.
// d_out (128 MB f32) doubles as scratch:
//   xn_t bf16 64MB (dead after QKV); then S partials f32 4x16MB=64MB
//   (written after xn_t dead). Final proj kernel rewrites all of d_out.
#define OFF_WQ    0ULL
#define OFF_WP    0x180000ULL
#define OFF_STATS 0x200000ULL
#define OFF_Q     0x400000ULL
#define OFF_K     (OFF_Q  + 0x4000000ULL)
#define OFF_VT    (OFF_K  + 0x4000000ULL)
#define OFF_ATT   OFF_Q
#define OFF_OT    OFF_K

typedef __attribute__((address_space(1))) const void* as1cvp;
typedef __attribute__((address_space(3))) void* as3vp;

__device__ inline void gload_lds16(const void* g, void* l) {
  __builtin_amdgcn_global_load_lds((as1cvp)g, (as3vp)l, 16, 0, 0);
}

// ---------------- K0: fp32 weights -> bf16 ----------------
__global__ __launch_bounds__(256) void cvt_weights(const float* __restrict__ wq,
                                                   const float* __restrict__ wp,
                                                   bf16* __restrict__ oq,
                                                   bf16* __restrict__ op) {
  int i = blockIdx.x * 256 + threadIdx.x;
  if (i < 1536 * 512) oq[i] = __float2bfloat16(wq[i]);
  if (i < 512 * 512)  op[i] = __float2bfloat16(wp[i]);
}

// ---------------- K1: GroupNorm stats ----------------
__global__ __launch_bounds__(256) void gn_stats(const float* __restrict__ x,
                                                float* __restrict__ stats) {
  const int bg = blockIdx.x;  // b*8+g, 128 blocks
  const float4* p = (const float4*)(x + (size_t)bg * GRP_ELEMS);
  float s = 0.f, q = 0.f;
  for (int i = threadIdx.x; i < GRP_ELEMS / 4; i += 256) {
    float4 v = p[i];
    s += v.x + v.y + v.z + v.w;
    q += v.x * v.x + v.y * v.y + v.z * v.z + v.w * v.w;
  }
  for (int off = 32; off; off >>= 1) { s += __shfl_xor(s, off); q += __shfl_xor(q, off); }
  __shared__ float red[8];
  int w = threadIdx.x >> 6;
  if ((threadIdx.x & 63) == 0) { red[w] = s; red[4 + w] = q; }
  __syncthreads();
  if (threadIdx.x == 0) {
    float S = red[0] + red[1] + red[2] + red[3];
    float Q = red[4] + red[5] + red[6] + red[7];
    float mean = S * (1.f / GRP_ELEMS);
    float var  = Q * (1.f / GRP_ELEMS) - mean * mean;
    stats[bg * 2]     = mean;
    stats[bg * 2 + 1] = rsqrtf(var + 1e-5f);
  }
}

// ---------------- K2: normalize + affine + transpose -> xn_t (b,n,c) bf16 ----
__global__ __launch_bounds__(256) void gn_apply_t(const float* __restrict__ x,
                                                  const float* __restrict__ stats,
                                                  const float* __restrict__ nw,
                                                  const float* __restrict__ nb,
                                                  bf16* __restrict__ xnt) {
  const int nt = blockIdx.x;   // n tile [0,64)
  const int ct = blockIdx.y;   // c tile == group [0,8)
  const int b  = blockIdx.z;
  __shared__ float tile[64][65];
  const float mean = stats[(b * NG + ct) * 2];
  const float rstd = stats[(b * NG + ct) * 2 + 1];
  const int col = threadIdx.x & 63;
  const int r4  = threadIdx.x >> 6;
#pragma unroll
  for (int p = 0; p < 16; ++p) {
    int cl = p * 4 + r4;
    int c  = ct * 64 + cl;
    float g  = nw[c] * rstd;
    float sh = nb[c] - mean * g;
    float v  = x[((size_t)b * C_ + c) * N_ + nt * 64 + col];
    tile[cl][col] = v * g + sh;
  }
  __syncthreads();
#pragma unroll
  for (int p = 0; p < 16; ++p) {
    int nl = p * 4 + r4;
    xnt[((size_t)b * N_ + nt * 64 + nl) * C_ + ct * 64 + col] =
        __float2bfloat16(tile[col][nl]);
  }
}

// ---------------- generic NT bf16 GEMM, 128x128 tile, BK=32 ----------------
// C[M,N] = A[M,K] * B[N,K]^T.  lda/ldb = row strides (may exceed loop K for
// split-K).  4 waves (2x2), each 64x64 = 4x4 frags of mfma_f32_16x16x32_bf16.
// MODE 0: QKV  grid(12,512):  x=M-tile FAST (12 consecutive blocks share one
//         B-panel -> B fetched from HBM once), y=N-tile. Outputs q,k,(b,c,n)
//         and v_t (b,n,c), +bias.
// MODE 1: QK^T grid(4,4,64): z = batch*4+part, split-K over n (4x1024).
//         Writes f32 partial S_part[part] * alpha.
// MODE 2: PV   grid(4,32,16): per batch. O_t (b,n,c) bf16.
// MODE 3: proj grid(4,512):  x=M-tile FAST (B-panel reuse). out f32 =
//         acc + bias[row] + resid.
template<int MODE>
__global__ __launch_bounds__(256) void gemm_nt(
    const bf16* __restrict__ Ag, const bf16* __restrict__ Bg,
    int K, int lda, int ldb,
    long long sA, long long sB,
    const float* __restrict__ bias, float alpha,
    void* __restrict__ o0, void* __restrict__ o1, void* __restrict__ o2,
    const float* __restrict__ resid) {
  __shared__ __align__(16) bf16 As[128 * 32];
  __shared__ __align__(16) bf16 Bs[128 * 32];
  int bx, by, bz, part;
  if constexpr (MODE == 0 || MODE == 3) {        // M-tile fastest for B reuse
    by = blockIdx.x; bx = blockIdx.y; bz = 0; part = 0;
  } else if constexpr (MODE == 1) {              // split-K over n
    bx = blockIdx.x; by = blockIdx.y; bz = blockIdx.z >> 2; part = blockIdx.z & 3;
  } else {
    bx = blockIdx.x; by = blockIdx.y; bz = blockIdx.z; part = 0;
  }
  const bf16* A = Ag + (size_t)bz * sA + (size_t)by * 128 * lda + (size_t)part * 1024;
  const bf16* B = Bg + (size_t)bz * sB + (size_t)bx * 128 * ldb + (size_t)part * 1024;
  const int tid  = threadIdx.x;
  const int lane = tid & 63;
  const int wv   = tid >> 6;
  const int wr = wv >> 1, wc = wv & 1;
  const int r0 = wr * 64, c0 = wc * 64;
  const int mrow = lane & 15, krow = lane >> 4;
  const int i0 = tid, i1 = tid + 256;

  f32x4 acc[4][4];
#pragma unroll
  for (int mi = 0; mi < 4; ++mi)
#pragma unroll
    for (int ni = 0; ni < 4; ++ni)
#pragma unroll
      for (int r = 0; r < 4; ++r) acc[mi][ni][r] = 0.f;

  for (int k0 = 0; k0 < K; k0 += 32) {
    // stage 128x32 A and B tiles; rows contiguous 64B in global (K-major)
    gload_lds16(A + (size_t)(i0 >> 2) * lda + k0 + (i0 & 3) * 8, (char*)As + i0 * 16);
    gload_lds16(A + (size_t)(i1 >> 2) * lda + k0 + (i1 & 3) * 8, (char*)As + i1 * 16);
    gload_lds16(B + (size_t)(i0 >> 2) * ldb + k0 + (i0 & 3) * 8, (char*)Bs + i0 * 16);
    gload_lds16(B + (size_t)(i1 >> 2) * ldb + k0 + (i1 & 3) * 8, (char*)Bs + i1 * 16);
    __syncthreads();  // compiler emits vmcnt(0) drain before barrier
    short8 af[4], bf_[4];
#pragma unroll
    for (int mi = 0; mi < 4; ++mi)
      af[mi] = *(const short8*)((const char*)As + (r0 + mi * 16 + mrow) * 64 + krow * 16);
#pragma unroll
    for (int ni = 0; ni < 4; ++ni)
      bf_[ni] = *(const short8*)((const char*)Bs + (c0 + ni * 16 + mrow) * 64 + krow * 16);
#pragma unroll
    for (int mi = 0; mi < 4; ++mi)
#pragma unroll
      for (int ni = 0; ni < 4; ++ni)
        acc[mi][ni] = __builtin_amdgcn_mfma_f32_16x16x32_bf16(af[mi], bf_[ni],
                                                              acc[mi][ni], 0, 0, 0);
    __syncthreads();
  }

  // epilogue: C(row,col) with row=(lane>>4)*4+r, col=lane&15 per 16x16 frag
#pragma unroll
  for (int mi = 0; mi < 4; ++mi) {
#pragma unroll
    for (int ni = 0; ni < 4; ++ni) {
      const int col_l = c0 + ni * 16 + mrow;
#pragma unroll
      for (int r = 0; r < 4; ++r) {
        const int row_l = r0 + mi * 16 + krow * 4 + r;
        float v = acc[mi][ni][r];
        if constexpr (MODE == 0) {
          int o = by * 128 + row_l;                // 0..1536
          v += bias[o];
          int j = bx * 128 + col_l;                // 0..65536
          int bidx = j >> 12, n = j & 4095;
          int which = o >> 9, ol = o & 511;
          if (which == 0)
            ((bf16*)o0)[((size_t)bidx * C_ + ol) * N_ + n] = __float2bfloat16(v);
          else if (which == 1)
            ((bf16*)o1)[((size_t)bidx * C_ + ol) * N_ + n] = __float2bfloat16(v);
          else
            ((bf16*)o2)[((size_t)bidx * N_ + n) * C_ + ol] = __float2bfloat16(v);
        } else if constexpr (MODE == 1) {
          int row = by * 128 + row_l, colg = bx * 128 + col_l;
          ((float*)o0)[(size_t)part * SPART_STRIDE + (size_t)bz * 262144 +
                       row * 512 + colg] = v * alpha;
        } else if constexpr (MODE == 2) {
          int row = by * 128 + row_l, colg = bx * 128 + col_l;
          ((bf16*)o0)[((size_t)bz * N_ + row) * C_ + colg] = __float2bfloat16(v);
        } else {
          int o = by * 128 + row_l;
          int j = bx * 128 + col_l;
          int bidx = j >> 12, n = j & 4095;
          size_t addr = ((size_t)bidx * C_ + o) * N_ + n;
          ((float*)o0)[addr] = v + bias[o] + resid[addr];
        }
      }
    }
  }
}

// ---------------- K5: row softmax over 4 split-K partials -> attn bf16 ------
__global__ __launch_bounds__(256) void softmax_rows(const float* __restrict__ S,
                                                    bf16* __restrict__ att) {
  const int row  = blockIdx.x * 4 + (threadIdx.x >> 6);  // b*512 + c
  const int lane = threadIdx.x & 63;
  const float* p = S + (size_t)row * 512;
  float v[8];
  float mx = -1e30f;
#pragma unroll
  for (int i = 0; i < 8; ++i) {
    int idx = lane + i * 64;
    v[i] = p[idx] + p[SPART_STRIDE + idx] + p[2 * SPART_STRIDE + idx] +
           p[3 * SPART_STRIDE + idx];
    mx = fmaxf(mx, v[i]);
  }
  for (int off = 32; off; off >>= 1) mx = fmaxf(mx, __shfl_xor(mx, off));
  float s = 0.f;
#pragma unroll
  for (int i = 0; i < 8; ++i) { v[i] = __expf(v[i] - mx); s += v[i]; }
  for (int off = 32; off; off >>= 1) s += __shfl_xor(s, off);
  float inv = 1.f / s;
  bf16* q = att + (size_t)row * 512;
#pragma unroll
  for (int i = 0; i < 8; ++i) q[lane + i * 64] = __float2bfloat16(v[i] * inv);
}

extern "C" void kernel_launch(void* const* d_in, const int* in_sizes, int n_in,
                              void* d_out, int out_size, void* d_ws, size_t ws_size,
                              hipStream_t stream) {
  const float* x      = (const float*)d_in[0];
  const float* norm_w = (const float*)d_in[1];
  const float* norm_b = (const float*)d_in[2];
  const float* qkv_w  = (const float*)d_in[3];
  const float* qkv_b  = (const float*)d_in[4];
  const float* proj_w = (const float*)d_in[5];
  const float* proj_b = (const float*)d_in[6];
  float* out = (float*)d_out;
  char* ws = (char*)d_ws;

  bf16*  wq    = (bf16*)(ws + OFF_WQ);
  bf16*  wp    = (bf16*)(ws + OFF_WP);
  float* stats = (float*)(ws + OFF_STATS);
  bf16*  q     = (bf16*)(ws + OFF_Q);
  bf16*  k     = (bf16*)(ws + OFF_K);
  bf16*  vt    = (bf16*)(ws + OFF_VT);
  bf16*  att   = (bf16*)(ws + OFF_ATT);   // aliases Q (dead after QK^T)
  bf16*  ot    = (bf16*)(ws + OFF_OT);    // aliases K (dead after QK^T)
  // d_out doubles as scratch for dead-range intermediates:
  bf16*  xnt   = (bf16*)d_out;            // 64 MB, dead after QKV GEMM
  float* S     = (float*)d_out;           // 4 x 16 MB partials, after xnt dead

  cvt_weights<<<3072, 256, 0, stream>>>(qkv_w, proj_w, wq, wp);
  gn_stats<<<128, 256, 0, stream>>>(x, stats);
  gn_apply_t<<<dim3(64, 8, 16), 256, 0, stream>>>(x, stats, norm_w, norm_b, xnt);
  // QKV: M=1536 (o), N=65536 (b*n), K=512; grid x=M-tiles (fast) for B reuse
  gemm_nt<0><<<dim3(12, 512, 1), 256, 0, stream>>>(wq, xnt, 512, 512, 512, 0, 0,
                                                   qkv_b, 1.f, q, k, vt, nullptr);
  // QK^T split-K: M=N=512 (c,d), K=4x1024 (n); z = batch*4+part
  gemm_nt<1><<<dim3(4, 4, 64), 256, 0, stream>>>(q, k, 1024, 4096, 4096,
                                                 512LL * 4096, 512LL * 4096,
                                                 nullptr, kScale, S, nullptr,
                                                 nullptr, nullptr);
  softmax_rows<<<2048, 256, 0, stream>>>(S, att);
  // PV per batch: M=4096 (n), N=512 (c), K=512 (d); A=v_t, B=attn
  gemm_nt<2><<<dim3(4, 32, 16), 256, 0, stream>>>(vt, att, 512, 512, 512,
                                                  4096LL * 512, 512LL * 512,
                                                  nullptr, 1.f, ot, nullptr,
                                                  nullptr, nullptr);
  // proj: M=512 (o), N=65536 (b*n), K=512 (c); grid x=M-tiles (fast)
  gemm_nt<3><<<dim3(4, 512, 1), 256, 0, stream>>>(wp, ot, 512, 512, 512, 0, 0,
                                                  proj_b, 1.f, out, nullptr,
                                                  nullptr, x);
}